// Round 4
// baseline (70.468 us; speedup 1.0000x reference)
//
#include <hip/hip_runtime.h>

#define NROWS  50000
#define NF     32
#define NTREES 300
#define NINT   63
#define NLEAF  64
#define LRATE  0.1f
#define RPB    256     // rows per block == threads per block
#define TPG    12      // trees per group (multiple of 6 for ILP-6 and of 3 classes)
#define TG     25      // tree groups (grid.y); TPG*TG == NTREES

__global__ void gb_init_out(const float* __restrict__ initp,
                            float* __restrict__ out, int n) {
    int i = blockIdx.x * blockDim.x + threadIdx.x;
    if (i < n) out[i] = initp[i % 3];
}

__global__ __launch_bounds__(RPB, 3) void gb_forest(
    const float* __restrict__ x,      // [NROWS][NF]
    const int*   __restrict__ feat,   // [NTREES][NINT]
    const float* __restrict__ thr,    // [NTREES][NINT]
    const float* __restrict__ leaves, // [NTREES][NLEAF]
    float*       __restrict__ out)    // [NROWS][3]
{
    // 32 KB + 12 KB = 44 KB -> 3 blocks/CU (132 KB of 160)
    __shared__ float xs[NF][RPB];                 // read bank = tid%32, conflict-free
    __shared__ alignas(16) int2 nodes[TPG][128];  // 1-based heap: slot j (1..63) = internal
                                                  // node j-1 {feat, thr_bits};
                                                  // slot 64+k = {0, leaf_value_bits[k]}

    const int tid  = threadIdx.x;
    const int r0   = blockIdx.x * RPB;
    const int m0   = blockIdx.y * TPG;
    const int grow = r0 + tid;

    // --- stage x: per-thread own row (8x float4), transposed write (bank=tid%32) ---
    {
        const float4* xr = (const float4*)x +
            (size_t)(grow < NROWS ? grow : NROWS - 1) * (NF / 4);
        float4 v[8];
        #pragma unroll
        for (int k = 0; k < 8; ++k) v[k] = xr[k];
        #pragma unroll
        for (int k = 0; k < 8; ++k) {
            xs[k * 4 + 0][tid] = v[k].x;
            xs[k * 4 + 1][tid] = v[k].y;
            xs[k * 4 + 2][tid] = v[k].z;
            xs[k * 4 + 3][tid] = v[k].w;
        }
    }
    // --- stage nodes+leaves, 1-based layout (TPG*128 = 1536 int2) ---
    for (int i = tid; i < TPG * 128; i += RPB) {
        int tl = i >> 7, slot = i & 127;
        int2 v = make_int2(0, 0);
        if (slot >= 1 && slot < 64) {          // internal node slot j -> node j-1
            int gi = (m0 + tl) * NINT + (slot - 1);
            v.x = feat[gi];
            v.y = __float_as_int(thr[gi]);
        } else if (slot >= 64) {               // leaf slot 64+k -> leaf value k
            v.y = __float_as_int(leaves[(m0 + tl) * NLEAF + (slot - 64)]);
        }
        nodes[tl][i & 127] = v;
    }
    __syncthreads();

    // --- walk 6 trees concurrently; per level: ONE LDS latency (x-read and
    //     children-pair b128 issue together; child selected by cndmask) ---
    float acc0 = 0.f, acc1 = 0.f, acc2 = 0.f;
    #pragma unroll
    for (int g = 0; g < TPG; g += 6) {
        int   j[6];
        int2  cur[6];
        #pragma unroll
        for (int c = 0; c < 6; ++c) { j[c] = 1; cur[c] = nodes[g + c][1]; }

        #pragma unroll
        for (int d = 0; d < 6; ++d) {
            #pragma unroll
            for (int c = 0; c < 6; ++c) {
                const int2* nd = nodes[g + c];
                float xv  = xs[cur[c].x][tid];        // LDS b32, conflict-free
                int2  ch0 = nd[2 * j[c]];             // 16B-aligned pair ->
                int2  ch1 = nd[2 * j[c] + 1];         //   one ds_read_b128
                // sklearn: left iff x <= t -> right iff x > t
                bool right = xv > __int_as_float(cur[c].y);
                j[c]  = 2 * j[c] + (right ? 1 : 0);
                cur[c] = right ? ch1 : ch0;           // next (f,t) or leaf value
            }
        }
        // after 6 levels cur[c].y holds the selected leaf value
        #pragma unroll
        for (int c = 0; c < 6; ++c) {
            float lv = __int_as_float(cur[c].y);
            if (c % 3 == 0)      acc0 += lv;
            else if (c % 3 == 1) acc1 += lv;
            else                 acc2 += lv;
        }
    }

    if (grow < NROWS) {
        atomicAdd(&out[grow * 3 + 0], LRATE * acc0);
        atomicAdd(&out[grow * 3 + 1], LRATE * acc1);
        atomicAdd(&out[grow * 3 + 2], LRATE * acc2);
    }
}

extern "C" void kernel_launch(void* const* d_in, const int* in_sizes, int n_in,
                              void* d_out, int out_size, void* d_ws, size_t ws_size,
                              hipStream_t stream) {
    const float* x      = (const float*)d_in[0];
    const int*   feat   = (const int*)d_in[1];
    const float* thr    = (const float*)d_in[2];
    const float* leaves = (const float*)d_in[3];
    const float* initp  = (const float*)d_in[4];
    float* out = (float*)d_out;

    gb_init_out<<<(out_size + 255) / 256, 256, 0, stream>>>(initp, out, out_size);

    dim3 grid((NROWS + RPB - 1) / RPB, TG);
    gb_forest<<<grid, RPB, 0, stream>>>(x, feat, thr, leaves, out);
}

// Round 5
// 67.343 us; speedup vs baseline: 1.0464x; 1.0464x over previous
//
#include <hip/hip_runtime.h>

#define NROWS  50000
#define NF     32
#define NTREES 300
#define NINT   63
#define NLEAF  64
#define LRATE  0.1f
#define RPB    256     // rows per block == threads per block
#define TPG    12      // trees per group (multiple of 6 for ILP-6 and of 3 classes)
#define TG     25      // tree groups (grid.y); TPG*TG == NTREES

__global__ void gb_init_out(const float* __restrict__ initp,
                            float* __restrict__ out, int n) {
    int i = blockIdx.x * blockDim.x + threadIdx.x;
    if (i < n) out[i] = initp[i % 3];
}

__global__ __launch_bounds__(RPB, 4) void gb_forest(
    const float* __restrict__ x,      // [NROWS][NF]
    const int*   __restrict__ feat,   // [NTREES][NINT]
    const float* __restrict__ thr,    // [NTREES][NINT]
    const float* __restrict__ leaves, // [NTREES][NLEAF]
    float*       __restrict__ out)    // [NROWS][3]
{
    // 32768 + 5376 = 38144 B -> 4 blocks/CU (16 waves/CU)
    __shared__ float xs[NF][RPB];     // read bank = tid%32, conflict-free
    __shared__ int2  deep[TPG][56];   // 1-based slots 8..63 (0-based nodes 7..62)

    const int tid  = threadIdx.x;
    const int r0_  = blockIdx.x * RPB;
    const int m0   = blockIdx.y * TPG;
    const int grow = r0_ + tid;

    // --- stage x: per-thread own row (8x float4), transposed write (bank = tid%32) ---
    {
        const float4* xr = (const float4*)x +
            (size_t)(grow < NROWS ? grow : NROWS - 1) * (NF / 4);
        float4 v[8];
        #pragma unroll
        for (int k = 0; k < 8; ++k) v[k] = xr[k];
        #pragma unroll
        for (int k = 0; k < 8; ++k) {
            xs[k * 4 + 0][tid] = v[k].x;
            xs[k * 4 + 1][tid] = v[k].y;
            xs[k * 4 + 2][tid] = v[k].z;
            xs[k * 4 + 3][tid] = v[k].w;
        }
    }
    // --- stage deep nodes only (levels 3-5): slot j in [8,64) -> node j-1 ---
    for (int i = tid; i < TPG * 56; i += RPB) {
        int tl = i / 56, s = i - tl * 56;          // s = j - 8
        int gi = (m0 + tl) * NINT + (s + 7);       // 0-based node index j-1
        deep[tl][s] = make_int2(feat[gi], __float_as_int(thr[gi]));
    }
    __syncthreads();

    // --- walk 6 trees concurrently.
    //     Levels 0-2: node data is block-uniform -> scalar loads + cndmask
    //     selects (NO LDS node gather). Levels 3-5: LDS b64 gather. ---
    float acc0 = 0.f, acc1 = 0.f, acc2 = 0.f;
    #pragma unroll
    for (int g = 0; g < TPG; g += 6) {
        float lv[6];
        #pragma unroll
        for (int c = 0; c < 6; ++c) {
            const int tt = m0 + g + c;
            const int*   fb = feat + (size_t)tt * NINT;   // uniform base -> s_load
            const float* tb = thr  + (size_t)tt * NINT;

            // preload 7 shallow nodes into (scalar) registers
            int   f0v = fb[0], f1v = fb[1], f2v = fb[2], f3v = fb[3],
                  f4v = fb[4], f5v = fb[5], f6v = fb[6];
            float t0v = tb[0], t1v = tb[1], t2v = tb[2], t3v = tb[3],
                  t4v = tb[4], t5v = tb[5], t6v = tb[6];

            // level 0 (root = node 0)
            float xv0 = xs[f0v][tid];
            int b0 = (xv0 > t0v);
            // level 1: node 1+b0, selected via cndmask
            int   fA = b0 ? f2v : f1v;
            float tA = b0 ? t2v : t1v;
            float xv1 = xs[fA][tid];
            int b1 = (xv1 > tA);
            // level 2: node 3 + 2*b0 + b1
            int   fL = b1 ? f4v : f3v,  fH = b1 ? f6v : f5v;
            float tL = b1 ? t4v : t3v,  tH = b1 ? t6v : t5v;
            int   fB = b0 ? fH : fL;
            float tB = b0 ? tH : tL;
            float xv2 = xs[fB][tid];
            int b2 = (xv2 > tB);

            // 1-based slot after 3 levels: j in [8,16)
            int j = 8 + 4 * b0 + 2 * b1 + b2;

            // levels 3-5 from LDS (divergent, 2-way max at depth 5 -> free)
            #pragma unroll
            for (int d = 3; d < 6; ++d) {
                int2 nd  = deep[g + c][j - 8];
                float xv = xs[nd.x][tid];
                j = 2 * j + (int)(xv > __int_as_float(nd.y));
            }
            // j in [64,128): leaf index j-64
            lv[c] = leaves[(size_t)tt * NLEAF + (j - 64)];
        }
        acc0 += lv[0] + lv[3];
        acc1 += lv[1] + lv[4];
        acc2 += lv[2] + lv[5];
    }

    if (grow < NROWS) {
        atomicAdd(&out[grow * 3 + 0], LRATE * acc0);
        atomicAdd(&out[grow * 3 + 1], LRATE * acc1);
        atomicAdd(&out[grow * 3 + 2], LRATE * acc2);
    }
}

extern "C" void kernel_launch(void* const* d_in, const int* in_sizes, int n_in,
                              void* d_out, int out_size, void* d_ws, size_t ws_size,
                              hipStream_t stream) {
    const float* x      = (const float*)d_in[0];
    const int*   feat   = (const int*)d_in[1];
    const float* thr    = (const float*)d_in[2];
    const float* leaves = (const float*)d_in[3];
    const float* initp  = (const float*)d_in[4];
    float* out = (float*)d_out;

    gb_init_out<<<(out_size + 255) / 256, 256, 0, stream>>>(initp, out, out_size);

    dim3 grid((NROWS + RPB - 1) / RPB, TG);
    gb_forest<<<grid, RPB, 0, stream>>>(x, feat, thr, leaves, out);
}